// Round 4
// baseline (822.945 us; speedup 1.0000x reference)
//
#include <hip/hip_runtime.h>

#define TT 36
#define DD 64
#define NN 207
#define BBATCH 16
#define LN_EPS 1e-5f

__device__ __forceinline__ float bl(unsigned u) { return __uint_as_float(u << 16); }
__device__ __forceinline__ float bh(unsigned u) { return __uint_as_float(u & 0xFFFF0000u); }
__device__ __forceinline__ unsigned short f2b(float f) {
    unsigned u = __float_as_uint(f);
    return (unsigned short)((u + 0x7FFFu + ((u >> 16) & 1u)) >> 16);
}

__global__ __launch_bounds__(512, 6) void fused_attn4(
    const float* __restrict__ X, const float* __restrict__ Qg,
    const float* __restrict__ Kg, const float* __restrict__ Vg,
    const float* __restrict__ Wv, const float* __restrict__ bv,
    const float* __restrict__ Wo, const float* __restrict__ bo,
    const float* __restrict__ cqw, const float* __restrict__ cqb_g,
    const float* __restrict__ ckw,
    const float* __restrict__ gam, const float* __restrict__ bet,
    float* __restrict__ out)
{
    __shared__ unsigned short Qs[TT][72];   // bf16, rows 144B (16B-aligned)
    __shared__ unsigned short Ks[TT][72];
    __shared__ unsigned short Vh[TT][64];   // bf16 projected V (64 cols! rows 128B)
    __shared__ float VrCtx[TT][68];         // raw V (f32), later ctx (f32)
    __shared__ float M_s[25][28];           // 0.125*Wq^T Wk ; row 24 = 0.125*Wk^T cqb
    __shared__ __align__(16) unsigned char Ubuf[23040]; // Wq/Wk f32 staging, later P bf16 [8][36][40]
    __shared__ float bv_s[64], bo_s[64], g_s[64], be_s[64], cqb_s[64];

    float* Wq_s = (float*)Ubuf;             // [64][24]
    float* Wk_s = Wq_s + 64 * 24;
    unsigned short* P_s = (unsigned short*)Ubuf;  // [8][36][40] bf16 (unnormalized e)

    const int tid  = threadIdx.x;
    const int lane = tid & 63;
    const int wave = tid >> 6;
    const int b    = blockIdx.x / NN;
    const int n    = blockIdx.x % NN;

    // ---- staging ----
    const float4* Q4 = (const float4*)(Qg + (size_t)(b * TT * NN + n) * DD);
    const float4* K4 = (const float4*)(Kg + (size_t)(b * TT * NN + n) * DD);
    const float4* V4 = (const float4*)(Vg + (size_t)(b * TT * NN + n) * DD);
    for (int idx = tid; idx < TT * 16; idx += 512) {
        int t = idx >> 4, o = idx & 15;
        float4 q = Q4[t * 3312 + o];
        float4 k = K4[t * 3312 + o];
        ((float4*)&VrCtx[t][0])[o] = V4[t * 3312 + o];
        ushort4 qp = {f2b(q.x), f2b(q.y), f2b(q.z), f2b(q.w)};
        ushort4 kp = {f2b(k.x), f2b(k.y), f2b(k.z), f2b(k.w)};
        *(ushort4*)&Qs[t][o * 4] = qp;
        *(ushort4*)&Ks[t][o * 4] = kp;
    }
    for (int idx = tid; idx < 768; idx += 512) {
        if (idx < 384) ((float4*)Wq_s)[idx]       = ((const float4*)cqw)[idx];
        else           ((float4*)Wk_s)[idx - 384] = ((const float4*)ckw)[idx - 384];
    }
    if (tid < 64) {
        bv_s[tid] = bv[tid]; bo_s[tid] = bo[tid];
        g_s[tid] = gam[tid]; be_s[tid] = bet[tid];
        cqb_s[tid] = cqb_g[tid];
    }
    __syncthreads();

    // ---- M = 0.125 * Wq^T Wk (row 24: 0.125 * Wk^T cqb) ----
    for (int u = tid; u < 600; u += 512) {
        int j = u / 24, j2 = u - j * 24;
        float acc = 0.f;
        if (j < 24) {
            for (int c = 0; c < 64; ++c) acc += Wq_s[c * 24 + j] * Wk_s[c * 24 + j2];
        } else {
            for (int c = 0; c < 64; ++c) acc += cqb_s[c] * Wk_s[c * 24 + j2];
        }
        M_s[j][j2] = acc * 0.125f;
    }

    // ---- Vh = Vr @ Wv^T + bv (lane = out col, waves stride t) -> bf16 ----
    {
        float4 wrow[16];
        const float4* wr = (const float4*)(Wv + lane * DD);
        #pragma unroll
        for (int j = 0; j < 16; ++j) wrow[j] = wr[j];
        for (int t = wave; t < TT; t += 8) {
            float acc = bv_s[lane];
            const float4* vr = (const float4*)&VrCtx[t][0];
            #pragma unroll
            for (int j = 0; j < 16; ++j) {
                float4 v = vr[j];
                acc += v.x * wrow[j].x + v.y * wrow[j].y + v.z * wrow[j].z + v.w * wrow[j].w;
            }
            Vh[t][lane] = f2b(acc);
        }
    }
    __syncthreads();   // M, Vh ready; Wq/Wk region reusable as P

    // ---- per-wave (wave = head): R in regs -> e = exp(S) rows -> P(bf16, zero-filled) ----
    {
        const int h = wave, h8 = h * 8;
        const bool kvalid = lane < TT;
        const int k = kvalid ? lane : 0;

        float akr[3][8];
        #pragma unroll
        for (int kt = 0; kt < 3; ++kt) {
            int row = k + kt - 2;
            if (row >= 0 && kvalid) {
                uint4 w = *(const uint4*)&Ks[row][h8];
                akr[kt][0] = bl(w.x); akr[kt][1] = bh(w.x);
                akr[kt][2] = bl(w.y); akr[kt][3] = bh(w.y);
                akr[kt][4] = bl(w.z); akr[kt][5] = bh(w.z);
                akr[kt][6] = bl(w.w); akr[kt][7] = bh(w.w);
            } else {
                #pragma unroll
                for (int i = 0; i < 8; ++i) akr[kt][i] = 0.f;
            }
        }

        float R[25];
        #pragma unroll
        for (int j = 0; j < 25; ++j) {
            const float4* mr = (const float4*)&M_s[j][0];
            float4 m0 = mr[0], m1 = mr[1], m2 = mr[2], m3 = mr[3], m4 = mr[4], m5 = mr[5];
            float m[24] = {m0.x,m0.y,m0.z,m0.w, m1.x,m1.y,m1.z,m1.w, m2.x,m2.y,m2.z,m2.w,
                           m3.x,m3.y,m3.z,m3.w, m4.x,m4.y,m4.z,m4.w, m5.x,m5.y,m5.z,m5.w};
            float acc = 0.f;
            #pragma unroll
            for (int i = 0; i < 8; ++i)
                acc += akr[0][i] * m[i*3] + akr[1][i] * m[i*3+1] + akr[2][i] * m[i*3+2];
            R[j] = acc;
        }

        auto sstep = [&](int q, float (&am2)[8], float (&am1)[8], float (&cur)[8]) {
            uint4 w = *(const uint4*)&Qs[q][h8];
            cur[0] = bl(w.x); cur[1] = bh(w.x);
            cur[2] = bl(w.y); cur[3] = bh(w.y);
            cur[4] = bl(w.z); cur[5] = bh(w.z);
            cur[6] = bl(w.w); cur[7] = bh(w.w);
            float s0 = R[24], s1 = 0.f, s2 = 0.f;
            #pragma unroll
            for (int i = 0; i < 8; ++i) {
                s0 += am2[i] * R[i*3];
                s1 += am1[i] * R[i*3+1];
                s2 += cur[i] * R[i*3+2];
            }
            float e = __expf(s0 + s1 + s2);
            if (kvalid)
                P_s[(h * TT + q) * 40 + k] = (k <= q) ? f2b(e) : (unsigned short)0;
        };

        float A0[8], A1[8], A2[8];
        #pragma unroll
        for (int i = 0; i < 8; ++i) { A0[i] = 0.f; A1[i] = 0.f; }
        for (int qb = 0; qb < TT; qb += 3) {
            sstep(qb,     A0, A1, A2);
            sstep(qb + 1, A1, A2, A0);
            sstep(qb + 2, A2, A0, A1);
        }
    }
    __syncthreads();

    // ---- ctx[q][h8+e] = (sum_k e * Vh) / (sum_k e), fixed-trip paired loop ----
    for (int id = tid; id < 576; id += 512) {
        int hh = id / 72, r = id - hh * 72, q = r >> 1, eh = r & 1;
        const unsigned* prow = (const unsigned*)(P_s + (hh * TT + q) * 40);
        const int vb = hh * 8 + eh * 4;
        float a0 = 0.f, a1 = 0.f, a2 = 0.f, a3 = 0.f, esum = 0.f;
        #pragma unroll
        for (int kp = 0; kp < 18; ++kp) {
            unsigned pw = prow[kp];
            float p0 = bl(pw), p1 = bh(pw);
            esum += p0 + p1;
            uint2 v0 = *(const uint2*)&Vh[2 * kp][vb];
            uint2 v1 = *(const uint2*)&Vh[2 * kp + 1][vb];
            a0 += p0 * bl(v0.x) + p1 * bl(v1.x);
            a1 += p0 * bh(v0.x) + p1 * bh(v1.x);
            a2 += p0 * bl(v0.y) + p1 * bl(v1.y);
            a3 += p0 * bh(v0.y) + p1 * bh(v1.y);
        }
        float inv = __frcp_rn(esum);
        float4 o = {a0 * inv, a1 * inv, a2 * inv, a3 * inv};
        *(float4*)&VrCtx[q][vb] = o;
    }
    __syncthreads();

    // ---- out = Ctx @ Wo^T + bo + X, LayerNorm ----
    {
        float4 wrow[16];
        const float4* wr = (const float4*)(Wo + lane * DD);
        #pragma unroll
        for (int j = 0; j < 16; ++j) wrow[j] = wr[j];
        for (int t = wave; t < TT; t += 8) {
            float acc = bo_s[lane];
            const float4* cr = (const float4*)&VrCtx[t][0];
            #pragma unroll
            for (int j = 0; j < 16; ++j) {
                float4 v = cr[j];
                acc += v.x * wrow[j].x + v.y * wrow[j].y + v.z * wrow[j].z + v.w * wrow[j].w;
            }
            size_t g = ((size_t)(b * TT + t) * NN + n) * DD + lane;
            acc += X[g];
            float s1 = acc, s2 = acc * acc;
            #pragma unroll
            for (int off = 32; off; off >>= 1) {
                s1 += __shfl_xor(s1, off);
                s2 += __shfl_xor(s2, off);
            }
            float mu  = s1 * (1.f / 64.f);
            float var = s2 * (1.f / 64.f) - mu * mu;
            out[g] = (acc - mu) * rsqrtf(var + LN_EPS) * g_s[lane] + be_s[lane];
        }
    }
}

extern "C" void kernel_launch(void* const* d_in, const int* in_sizes, int n_in,
                              void* d_out, int out_size, void* d_ws, size_t ws_size,
                              hipStream_t stream) {
    const float* X   = (const float*)d_in[0];
    const float* Q   = (const float*)d_in[1];
    const float* K   = (const float*)d_in[2];
    const float* V   = (const float*)d_in[3];
    const float* Wv  = (const float*)d_in[4];
    const float* bv  = (const float*)d_in[5];
    const float* Wo  = (const float*)d_in[6];
    const float* bo  = (const float*)d_in[7];
    const float* cqw = (const float*)d_in[8];
    const float* cqb = (const float*)d_in[9];
    const float* ckw = (const float*)d_in[10];
    // d_in[11] (conv_k_b) cancels in softmax -> unused
    const float* gam = (const float*)d_in[12];
    const float* bet = (const float*)d_in[13];
    float* out = (float*)d_out;

    dim3 grid(BBATCH * NN), block(512);
    hipLaunchKernelGGL(fused_attn4, grid, block, 0, stream,
                       X, Q, K, V, Wv, bv, Wo, bo, cqw, cqb, ckw, gam, bet, out);
}

// Round 5
// 234.764 us; speedup vs baseline: 3.5054x; 3.5054x over previous
//
#include <hip/hip_runtime.h>

#define TT 36
#define DD 64
#define NN 207
#define BBATCH 16
#define LN_EPS 1e-5f

__device__ __forceinline__ float bl(unsigned u) { return __uint_as_float(u << 16); }
__device__ __forceinline__ float bh(unsigned u) { return __uint_as_float(u & 0xFFFF0000u); }
__device__ __forceinline__ unsigned short f2b(float f) {
    unsigned u = __float_as_uint(f);
    return (unsigned short)((u + 0x7FFFu + ((u >> 16) & 1u)) >> 16);
}

__global__ __launch_bounds__(512, 4) void fused_attn5(
    const float* __restrict__ X, const float* __restrict__ Qg,
    const float* __restrict__ Kg, const float* __restrict__ Vg,
    const float* __restrict__ Wv, const float* __restrict__ bv,
    const float* __restrict__ Wo, const float* __restrict__ bo,
    const float* __restrict__ cqw, const float* __restrict__ cqb_g,
    const float* __restrict__ ckw,
    const float* __restrict__ gam, const float* __restrict__ bet,
    float* __restrict__ out)
{
    __shared__ unsigned short Qs[TT][72];   // bf16, rows 144B (16B-aligned)
    __shared__ unsigned short Ks[TT][72];
    __shared__ unsigned short Vh[TT][64];   // bf16 projected V (rows 128B)
    __shared__ float VrCtx[TT][68];         // raw V (f32), later ctx (f32)
    __shared__ float M_s[25][28];           // 0.125*Wq^T Wk ; row 24 = 0.125*Wk^T cqb
    __shared__ __align__(16) unsigned char Ubuf[23040]; // Wq/Wk f32 staging, later P bf16 [8][36][40]
    __shared__ float bv_s[64], bo_s[64], g_s[64], be_s[64], cqb_s[64];

    float* Wq_s = (float*)Ubuf;             // [64][24]
    float* Wk_s = Wq_s + 64 * 24;
    unsigned short* P_s = (unsigned short*)Ubuf;  // [8][36][40] bf16 (unnormalized e)

    const int tid  = threadIdx.x;
    const int lane = tid & 63;
    const int wave = tid >> 6;
    const int b    = blockIdx.x / NN;
    const int n    = blockIdx.x % NN;

    // ---- staging ----
    const float4* Q4 = (const float4*)(Qg + (size_t)(b * TT * NN + n) * DD);
    const float4* K4 = (const float4*)(Kg + (size_t)(b * TT * NN + n) * DD);
    const float4* V4 = (const float4*)(Vg + (size_t)(b * TT * NN + n) * DD);
    for (int idx = tid; idx < TT * 16; idx += 512) {
        int t = idx >> 4, o = idx & 15;
        float4 q = Q4[t * 3312 + o];
        float4 k = K4[t * 3312 + o];
        ((float4*)&VrCtx[t][0])[o] = V4[t * 3312 + o];
        ushort4 qp = {f2b(q.x), f2b(q.y), f2b(q.z), f2b(q.w)};
        ushort4 kp = {f2b(k.x), f2b(k.y), f2b(k.z), f2b(k.w)};
        *(ushort4*)&Qs[t][o * 4] = qp;
        *(ushort4*)&Ks[t][o * 4] = kp;
    }
    for (int idx = tid; idx < 768; idx += 512) {
        if (idx < 384) ((float4*)Wq_s)[idx]       = ((const float4*)cqw)[idx];
        else           ((float4*)Wk_s)[idx - 384] = ((const float4*)ckw)[idx - 384];
    }
    if (tid < 64) {
        bv_s[tid] = bv[tid]; bo_s[tid] = bo[tid];
        g_s[tid] = gam[tid]; be_s[tid] = bet[tid];
        cqb_s[tid] = cqb_g[tid];
    }
    __syncthreads();

    // ---- M = 0.125 * Wq^T Wk (row 24: 0.125 * Wk^T cqb) ----
    for (int u = tid; u < 600; u += 512) {
        int j = u / 24, j2 = u - j * 24;
        float acc = 0.f;
        if (j < 24) {
            for (int c = 0; c < 64; ++c) acc += Wq_s[c * 24 + j] * Wk_s[c * 24 + j2];
        } else {
            for (int c = 0; c < 64; ++c) acc += cqb_s[c] * Wk_s[c * 24 + j2];
        }
        M_s[j][j2] = acc * 0.125f;
    }

    // ---- Vh = Vr @ Wv^T + bv (lane = out col, waves stride t) -> bf16 ----
    {
        float4 wrow[16];
        const float4* wr = (const float4*)(Wv + lane * DD);
        #pragma unroll
        for (int j = 0; j < 16; ++j) wrow[j] = wr[j];
        for (int t = wave; t < TT; t += 8) {
            float acc = bv_s[lane];
            const float4* vr = (const float4*)&VrCtx[t][0];
            #pragma unroll
            for (int j = 0; j < 16; ++j) {
                float4 v = vr[j];
                acc += v.x * wrow[j].x + v.y * wrow[j].y + v.z * wrow[j].z + v.w * wrow[j].w;
            }
            Vh[t][lane] = f2b(acc);
        }
    }
    __syncthreads();   // M, Vh ready; Wq/Wk region reusable as P

    // ---- per-wave (wave = head): R in regs -> e = exp(S) rows -> P(bf16, zero-filled) ----
    {
        const int h = wave, h8 = h * 8;
        const bool kvalid = lane < TT;
        const int k = kvalid ? lane : 0;

        float akr[3][8];
        #pragma unroll
        for (int kt = 0; kt < 3; ++kt) {
            int row = k + kt - 2;
            if (row >= 0 && kvalid) {
                uint4 w = *(const uint4*)&Ks[row][h8];
                akr[kt][0] = bl(w.x); akr[kt][1] = bh(w.x);
                akr[kt][2] = bl(w.y); akr[kt][3] = bh(w.y);
                akr[kt][4] = bl(w.z); akr[kt][5] = bh(w.z);
                akr[kt][6] = bl(w.w); akr[kt][7] = bh(w.w);
            } else {
                #pragma unroll
                for (int i = 0; i < 8; ++i) akr[kt][i] = 0.f;
            }
        }

        float R[25];
        #pragma unroll
        for (int j = 0; j < 25; ++j) {
            const float4* mr = (const float4*)&M_s[j][0];
            float4 m0 = mr[0], m1 = mr[1], m2 = mr[2], m3 = mr[3], m4 = mr[4], m5 = mr[5];
            float m[24] = {m0.x,m0.y,m0.z,m0.w, m1.x,m1.y,m1.z,m1.w, m2.x,m2.y,m2.z,m2.w,
                           m3.x,m3.y,m3.z,m3.w, m4.x,m4.y,m4.z,m4.w, m5.x,m5.y,m5.z,m5.w};
            float acc = 0.f;
            #pragma unroll
            for (int i = 0; i < 8; ++i)
                acc += akr[0][i] * m[i*3] + akr[1][i] * m[i*3+1] + akr[2][i] * m[i*3+2];
            R[j] = acc;
        }

        auto sstep = [&](int q, float (&am2)[8], float (&am1)[8], float (&cur)[8]) {
            uint4 w = *(const uint4*)&Qs[q][h8];
            cur[0] = bl(w.x); cur[1] = bh(w.x);
            cur[2] = bl(w.y); cur[3] = bh(w.y);
            cur[4] = bl(w.z); cur[5] = bh(w.z);
            cur[6] = bl(w.w); cur[7] = bh(w.w);
            float s0 = R[24], s1 = 0.f, s2 = 0.f;
            #pragma unroll
            for (int i = 0; i < 8; ++i) {
                s0 += am2[i] * R[i*3];
                s1 += am1[i] * R[i*3+1];
                s2 += cur[i] * R[i*3+2];
            }
            float e = __expf(s0 + s1 + s2);
            if (kvalid)
                P_s[(h * TT + q) * 40 + k] = (k <= q) ? f2b(e) : (unsigned short)0;
        };

        float A0[8], A1[8], A2[8];
        #pragma unroll
        for (int i = 0; i < 8; ++i) { A0[i] = 0.f; A1[i] = 0.f; }
        for (int qb = 0; qb < TT; qb += 3) {
            sstep(qb,     A0, A1, A2);
            sstep(qb + 1, A1, A2, A0);
            sstep(qb + 2, A2, A0, A1);
        }
    }
    __syncthreads();

    // ---- ctx[q][h8+e] = (sum_k e * Vh) / (sum_k e), fixed-trip paired loop ----
    for (int id = tid; id < 576; id += 512) {
        int hh = id / 72, r = id - hh * 72, q = r >> 1, eh = r & 1;
        const unsigned* prow = (const unsigned*)(P_s + (hh * TT + q) * 40);
        const int vb = hh * 8 + eh * 4;
        float a0 = 0.f, a1 = 0.f, a2 = 0.f, a3 = 0.f, esum = 0.f;
        #pragma unroll
        for (int kp = 0; kp < 18; ++kp) {
            unsigned pw = prow[kp];
            float p0 = bl(pw), p1 = bh(pw);
            esum += p0 + p1;
            uint2 v0 = *(const uint2*)&Vh[2 * kp][vb];
            uint2 v1 = *(const uint2*)&Vh[2 * kp + 1][vb];
            a0 += p0 * bl(v0.x) + p1 * bl(v1.x);
            a1 += p0 * bh(v0.x) + p1 * bh(v1.x);
            a2 += p0 * bl(v0.y) + p1 * bl(v1.y);
            a3 += p0 * bh(v0.y) + p1 * bh(v1.y);
        }
        float inv = __frcp_rn(esum);
        float4 o = {a0 * inv, a1 * inv, a2 * inv, a3 * inv};
        *(float4*)&VrCtx[q][vb] = o;
    }
    __syncthreads();

    // ---- out = Ctx @ Wo^T + bo + X, LayerNorm ----
    {
        float4 wrow[16];
        const float4* wr = (const float4*)(Wo + lane * DD);
        #pragma unroll
        for (int j = 0; j < 16; ++j) wrow[j] = wr[j];
        for (int t = wave; t < TT; t += 8) {
            float acc = bo_s[lane];
            const float4* cr = (const float4*)&VrCtx[t][0];
            #pragma unroll
            for (int j = 0; j < 16; ++j) {
                float4 v = cr[j];
                acc += v.x * wrow[j].x + v.y * wrow[j].y + v.z * wrow[j].z + v.w * wrow[j].w;
            }
            size_t g = ((size_t)(b * TT + t) * NN + n) * DD + lane;
            acc += X[g];
            float s1 = acc, s2 = acc * acc;
            #pragma unroll
            for (int off = 32; off; off >>= 1) {
                s1 += __shfl_xor(s1, off);
                s2 += __shfl_xor(s2, off);
            }
            float mu  = s1 * (1.f / 64.f);
            float var = s2 * (1.f / 64.f) - mu * mu;
            out[g] = (acc - mu) * rsqrtf(var + LN_EPS) * g_s[lane] + be_s[lane];
        }
    }
}

extern "C" void kernel_launch(void* const* d_in, const int* in_sizes, int n_in,
                              void* d_out, int out_size, void* d_ws, size_t ws_size,
                              hipStream_t stream) {
    const float* X   = (const float*)d_in[0];
    const float* Q   = (const float*)d_in[1];
    const float* K   = (const float*)d_in[2];
    const float* V   = (const float*)d_in[3];
    const float* Wv  = (const float*)d_in[4];
    const float* bv  = (const float*)d_in[5];
    const float* Wo  = (const float*)d_in[6];
    const float* bo  = (const float*)d_in[7];
    const float* cqw = (const float*)d_in[8];
    const float* cqb = (const float*)d_in[9];
    const float* ckw = (const float*)d_in[10];
    // d_in[11] (conv_k_b) cancels in softmax -> unused
    const float* gam = (const float*)d_in[12];
    const float* bet = (const float*)d_in[13];
    float* out = (float*)d_out;

    dim3 grid(BBATCH * NN), block(512);
    hipLaunchKernelGGL(fused_attn5, grid, block, 0, stream,
                       X, Q, K, V, Wv, bv, Wo, bo, cqw, cqb, ckw, gam, bet, out);
}

// Round 6
// 192.984 us; speedup vs baseline: 4.2643x; 1.2165x over previous
//
#include <hip/hip_runtime.h>

#define TT 36
#define NN 207
#define LN_EPS 1e-5f

typedef __attribute__((ext_vector_type(8))) short short8;
typedef __attribute__((ext_vector_type(4))) float f32x4;

__device__ __forceinline__ float bl(unsigned u) { return __uint_as_float(u << 16); }
__device__ __forceinline__ unsigned short f2b(float f) {
    unsigned u = __float_as_uint(f);
    return (unsigned short)((u + 0x7FFFu + ((u >> 16) & 1u)) >> 16);
}
__device__ __forceinline__ short8 s8(uint4 u) { union { uint4 a; short8 b; } x; x.a = u; return x.b; }

__global__ __launch_bounds__(512, 4) void fused_attn6(
    const float* __restrict__ X, const float* __restrict__ Qg,
    const float* __restrict__ Kg, const float* __restrict__ Vg,
    const float* __restrict__ Wv, const float* __restrict__ bv,
    const float* __restrict__ Wo, const float* __restrict__ bo,
    const float* __restrict__ cqw, const float* __restrict__ cqb_g,
    const float* __restrict__ ckw,
    const float* __restrict__ gam, const float* __restrict__ bet,
    float* __restrict__ out)
{
    __shared__ __align__(16) unsigned short Qs[40 * 72];   // bf16, rows 36-39 zero
    __shared__ __align__(16) unsigned short Ks[40 * 72];
    __shared__ __align__(16) unsigned short VhT[64 * 40];  // bf16 projected-V TRANSPOSED [col][t], cols t=36..39 zero
    __shared__ __align__(16) float VrCtx[36 * 68];         // raw V f32, later ctx f32
    __shared__ __align__(16) unsigned short Mt[32 * 32];   // bf16: Mt[j2][j'] = 0.125*sum_c Wq[c][j']Wk[c][j2]; col 24 = vk
    __shared__ __align__(16) unsigned char Ubuf[23040];    // Wq/Wk f32 staging -> per-head Z scratch + P bf16 [8][36][40]
    __shared__ float bv_s[64], bo_s[64], g_s[64], be_s[64], cqb_s[64];

    float* Wq_s = (float*)Ubuf;            // [64][24]
    float* Wk_s = Wq_s + 64 * 24;
    unsigned short* P_s = (unsigned short*)Ubuf;

    const int tid  = threadIdx.x;
    const int lane = tid & 63;
    const int wave = tid >> 6;
    const int b    = blockIdx.x / NN;
    const int n    = blockIdx.x % NN;
    const uint4 z4 = {0u, 0u, 0u, 0u};

    // ================= staging =================
    const float4* Q4 = (const float4*)(Qg + (size_t)(b * TT * NN + n) * 64);
    const float4* K4 = (const float4*)(Kg + (size_t)(b * TT * NN + n) * 64);
    const float4* V4 = (const float4*)(Vg + (size_t)(b * TT * NN + n) * 64);
    for (int idx = tid; idx < TT * 16; idx += 512) {
        int t = idx >> 4, o = idx & 15;
        float4 q = Q4[t * 3312 + o];
        float4 k = K4[t * 3312 + o];
        ((float4*)&VrCtx[t * 68])[o] = V4[t * 3312 + o];
        ushort4 qp = {f2b(q.x), f2b(q.y), f2b(q.z), f2b(q.w)};
        ushort4 kp = {f2b(k.x), f2b(k.y), f2b(k.z), f2b(k.w)};
        *(ushort4*)&Qs[t * 72 + o * 4] = qp;
        *(ushort4*)&Ks[t * 72 + o * 4] = kp;
    }
    for (int idx = tid; idx < 768; idx += 512) {
        if (idx < 384) ((float4*)Wq_s)[idx]       = ((const float4*)cqw)[idx];
        else           ((float4*)Wk_s)[idx - 384] = ((const float4*)ckw)[idx - 384];
    }
    // zero pad rows 36-39 of Qs/Ks (576B each = 36 uint4)
    for (int idx = tid; idx < 72; idx += 512) {
        if (idx < 36) ((uint4*)&Qs[36 * 72])[idx] = z4;
        else          ((uint4*)&Ks[36 * 72])[idx - 36] = z4;
    }
    // zero Mt (128 uint4) and VhT cols 36-39
    for (int idx = tid; idx < 128; idx += 512) ((uint4*)Mt)[idx] = z4;
    if (tid < 64) { *(uint2*)&VhT[tid * 40 + 36] = make_uint2(0u, 0u); }
    if (tid < 64) {
        bv_s[tid] = bv[tid]; bo_s[tid] = bo[tid];
        g_s[tid] = gam[tid]; be_s[tid] = bet[tid];
        cqb_s[tid] = cqb_g[tid];
    }
    __syncthreads();

    // ================= Mt build (kt-major both sides) + Vh projection =================
    for (int u = tid; u < 600; u += 512) {
        int j2 = u / 25, jp = u - j2 * 25;
        int wkc = (j2 & 7) * 3 + (j2 >> 3);
        float acc = 0.f;
        if (jp < 24) {
            int wqc = (jp & 7) * 3 + (jp >> 3);
            for (int c = 0; c < 64; ++c) acc += Wq_s[c * 24 + wqc] * Wk_s[c * 24 + wkc];
        } else {
            for (int c = 0; c < 64; ++c) acc += cqb_s[c] * Wk_s[c * 24 + wkc];
        }
        Mt[j2 * 32 + jp] = f2b(acc * 0.125f);
    }
    {
        float4 wrow[16];
        const float4* wr = (const float4*)(Wv + lane * 64);
        #pragma unroll
        for (int j = 0; j < 16; ++j) wrow[j] = wr[j];
        for (int t = wave; t < TT; t += 8) {
            float acc = bv_s[lane];
            const float4* vr = (const float4*)&VrCtx[t * 68];
            #pragma unroll
            for (int j = 0; j < 16; ++j) {
                float4 v = vr[j];
                acc += v.x * wrow[j].x + v.y * wrow[j].y + v.z * wrow[j].z + v.w * wrow[j].w;
            }
            VhT[lane * 40 + t] = f2b(acc);  // transposed store
        }
    }
    __syncthreads();   // Mt, VhT ready; Ubuf (Wq/Wk) now free for Z/P

    // ================= per-wave (wave = head) MFMA chain =================
    const int h8 = wave * 8;
    const int g = lane >> 4, c15 = lane & 15;
    unsigned short* Ph = P_s + wave * 1440;      // own P region [36][40]; also Z scratch [36][32]

    // ---- Z = [Aq | 1] @ Mt^T  (36x32 @ 32x32) ----
    {
        uint4 BfZ[2];
        #pragma unroll
        for (int ct = 0; ct < 2; ++ct)
            BfZ[ct] = *(const uint4*)&Mt[(ct * 16 + c15) * 32 + g * 8];
        #pragma unroll
        for (int rt = 0; rt < 3; ++rt) {
            uint4 av;
            if (g == 3) { av = z4; av.x = 0x00003F80u; }   // bias column j'=24 -> 1.0
            else {
                int row = rt * 16 + c15 + g - 2;
                int rc = min(max(row, 0), 39);
                av = *(const uint4*)&Qs[rc * 72 + h8];
                if (row < 0) av = z4;
            }
            f32x4 zz[2];
            #pragma unroll
            for (int ct = 0; ct < 2; ++ct) {
                f32x4 zero = {0.f, 0.f, 0.f, 0.f};
                zz[ct] = __builtin_amdgcn_mfma_f32_16x16x32_bf16(s8(av), s8(BfZ[ct]), zero, 0, 0, 0);
            }
            #pragma unroll
            for (int ct = 0; ct < 2; ++ct)
                #pragma unroll
                for (int r = 0; r < 4; ++r) {
                    int q = rt * 16 + g * 4 + r;
                    if (q < 36) Ph[q * 32 + ct * 16 + c15] = f2b(zz[ct][r]);
                }
        }
    }
    __syncthreads();

    // ---- S = Z @ Ak^T (36x32 @ 32x36), exp, write P ----
    {
        uint4 BfS[3], AfS[3];
        #pragma unroll
        for (int ct = 0; ct < 3; ++ct) {
            uint4 v = z4;
            if (g < 3) {
                int row = ct * 16 + c15 + g - 2;
                int rc = min(max(row, 0), 39);
                v = *(const uint4*)&Ks[rc * 72 + h8];
                if (row < 0) v = z4;
            }
            BfS[ct] = v;
        }
        #pragma unroll
        for (int rt = 0; rt < 3; ++rt) {
            int rc = min(rt * 16 + c15, 35);
            AfS[rt] = *(const uint4*)&Ph[rc * 32 + g * 8];   // Z scratch read
        }
        __syncthreads();   // all Z reads complete before P overwrites Z region
        #pragma unroll
        for (int rt = 0; rt < 3; ++rt) {
            #pragma unroll
            for (int ct = 0; ct < 3; ++ct) {
                f32x4 zero = {0.f, 0.f, 0.f, 0.f};
                f32x4 s = __builtin_amdgcn_mfma_f32_16x16x32_bf16(s8(AfS[rt]), s8(BfS[ct]), zero, 0, 0, 0);
                #pragma unroll
                for (int r = 0; r < 4; ++r) {
                    int q = rt * 16 + g * 4 + r;
                    int k = ct * 16 + c15;
                    if (q < 36 && k < 40) {
                        float e = (k <= q) ? __expf(s[r]) : 0.f;
                        Ph[q * 40 + k] = f2b(e);
                    }
                }
            }
        }
    }

    // ---- ctx = P @ [Vh | 1] (36x64-K @ ..x16), col 8 = esum ----
    {
        const unsigned ONE2 = 0x3F803F80u;
        uint4 B0, B1;
        {
            int cc = min(h8 + c15, 63);
            if (c15 == 8) { B0 = make_uint4(ONE2, ONE2, ONE2, ONE2); B1 = make_uint4(ONE2, ONE2, 0u, 0u); }
            else {
                B0 = *(const uint4*)&VhT[cc * 40 + g * 8];
                B1 = (g == 0) ? *(const uint4*)&VhT[cc * 40 + 32] : z4;
            }
        }
        #pragma unroll
        for (int rt = 0; rt < 3; ++rt) {
            int rc = min(rt * 16 + c15, 35);
            uint4 A0 = *(const uint4*)&Ph[rc * 40 + g * 8];
            uint4 A1 = (g == 0) ? *(const uint4*)&Ph[rc * 40 + 32] : z4;
            f32x4 d = {0.f, 0.f, 0.f, 0.f};
            d = __builtin_amdgcn_mfma_f32_16x16x32_bf16(s8(A0), s8(B0), d, 0, 0, 0);
            d = __builtin_amdgcn_mfma_f32_16x16x32_bf16(s8(A1), s8(B1), d, 0, 0, 0);
            #pragma unroll
            for (int r = 0; r < 4; ++r) {
                int q = rt * 16 + g * 4 + r;
                float es = __shfl(d[r], (lane & 48) | 8);
                if (q < 36 && c15 < 8)
                    VrCtx[q * 68 + h8 + c15] = d[r] * __frcp_rn(es);
            }
        }
    }
    __syncthreads();

    // ================= out = Ctx @ Wo^T + bo + X, LayerNorm =================
    {
        float4 wrow[16];
        const float4* wr = (const float4*)(Wo + lane * 64);
        #pragma unroll
        for (int j = 0; j < 16; ++j) wrow[j] = wr[j];
        for (int t = wave; t < TT; t += 8) {
            float acc = bo_s[lane];
            const float4* cr = (const float4*)&VrCtx[t * 68];
            #pragma unroll
            for (int j = 0; j < 16; ++j) {
                float4 v = cr[j];
                acc += v.x * wrow[j].x + v.y * wrow[j].y + v.z * wrow[j].z + v.w * wrow[j].w;
            }
            size_t gidx = ((size_t)(b * TT + t) * NN + n) * 64 + lane;
            acc += X[gidx];
            float s1 = acc, s2 = acc * acc;
            #pragma unroll
            for (int off = 32; off; off >>= 1) {
                s1 += __shfl_xor(s1, off);
                s2 += __shfl_xor(s2, off);
            }
            float mu  = s1 * (1.f / 64.f);
            float var = s2 * (1.f / 64.f) - mu * mu;
            out[gidx] = (acc - mu) * rsqrtf(var + LN_EPS) * g_s[lane] + be_s[lane];
        }
    }
}

extern "C" void kernel_launch(void* const* d_in, const int* in_sizes, int n_in,
                              void* d_out, int out_size, void* d_ws, size_t ws_size,
                              hipStream_t stream) {
    const float* X   = (const float*)d_in[0];
    const float* Q   = (const float*)d_in[1];
    const float* K   = (const float*)d_in[2];
    const float* V   = (const float*)d_in[3];
    const float* Wv  = (const float*)d_in[4];
    const float* bv  = (const float*)d_in[5];
    const float* Wo  = (const float*)d_in[6];
    const float* bo  = (const float*)d_in[7];
    const float* cqw = (const float*)d_in[8];
    const float* cqb = (const float*)d_in[9];
    const float* ckw = (const float*)d_in[10];
    // d_in[11] (conv_k_b) cancels in softmax -> unused
    const float* gam = (const float*)d_in[12];
    const float* bet = (const float*)d_in[13];
    float* out = (float*)d_out;

    dim3 grid(16 * NN), block(512);
    hipLaunchKernelGGL(fused_attn6, grid, block, 0, stream,
                       X, Q, K, V, Wv, bv, Wo, bo, cqw, cqb, ckw, gam, bet, out);
}

// Round 7
// 115.245 us; speedup vs baseline: 7.1408x; 1.6746x over previous
//
#include <hip/hip_runtime.h>

#define TT 36
#define NN 207
#define LN_EPS 1e-5f

typedef __attribute__((ext_vector_type(8))) short short8;
typedef __attribute__((ext_vector_type(4))) float f32x4;

__device__ __forceinline__ unsigned short f2b(float f) {
    unsigned u = __float_as_uint(f);
    return (unsigned short)((u + 0x7FFFu + ((u >> 16) & 1u)) >> 16);
}
__device__ __forceinline__ short8 s8(uint4 u) { union { uint4 a; short8 b; } x; x.a = u; return x.b; }

__global__ __launch_bounds__(512, 4) void fused_attn7(
    const float* __restrict__ X, const float* __restrict__ Qg,
    const float* __restrict__ Kg, const float* __restrict__ Vg,
    const float* __restrict__ Wv, const float* __restrict__ bv,
    const float* __restrict__ Wo, const float* __restrict__ bo,
    const float* __restrict__ cqw, const float* __restrict__ cqb_g,
    const float* __restrict__ ckw,
    const float* __restrict__ gam, const float* __restrict__ bet,
    float* __restrict__ out)
{
    __shared__ __align__(16) unsigned short Qs[40 * 72];   // bf16, rows 36-39 zero, 144B rows
    __shared__ __align__(16) unsigned short Ks[40 * 72];
    __shared__ __align__(16) unsigned short VhT[64 * 40];  // projected V transposed [o][t], t=36..39 zero
    __shared__ __align__(16) unsigned short Mt[32 * 40];   // kt-major 0.125*Wq^T Wk; col24=vk; stride 40
    __shared__ __align__(16) unsigned short Wv16[64 * 72]; // Wv bf16 [o][i]
    __shared__ __align__(16) unsigned short Wo16[64 * 72];
    __shared__ __align__(16) unsigned short Ctx16[36 * 72];// ctx bf16 rows
    __shared__ __align__(16) unsigned char  VsOut[36 * 68 * 4]; // Vs bf16 [36][72] -> OutS f32 [36][68]
    __shared__ __align__(16) unsigned char  Ubuf[23040];   // Wq/Wk f32 staging -> per-wave Z/P [36][40] bf16
    __shared__ float cqb_s[64], g_s[64], be_s[64];

    unsigned short* Vs   = (unsigned short*)VsOut;
    float*          OutS = (float*)VsOut;
    float* Wq_s = (float*)Ubuf;            // [64][24]
    float* Wk_s = Wq_s + 64 * 24;
    unsigned short* P_s = (unsigned short*)Ubuf;

    const int tid  = threadIdx.x;
    const int lane = tid & 63;
    const int wave = tid >> 6;
    const int g    = lane >> 4, c15 = lane & 15;
    const int b    = blockIdx.x / NN;
    const int n    = blockIdx.x % NN;
    const uint4 z4 = {0u, 0u, 0u, 0u};

    // ================= staging =================
    const float4* Q4 = (const float4*)(Qg + (size_t)(b * TT * NN + n) * 64);
    const float4* K4 = (const float4*)(Kg + (size_t)(b * TT * NN + n) * 64);
    const float4* V4 = (const float4*)(Vg + (size_t)(b * TT * NN + n) * 64);
    for (int idx = tid; idx < TT * 16; idx += 512) {
        int t = idx >> 4, o = idx & 15;
        float4 q = Q4[t * 3312 + o];
        float4 k = K4[t * 3312 + o];
        float4 v = V4[t * 3312 + o];
        ushort4 qp = {f2b(q.x), f2b(q.y), f2b(q.z), f2b(q.w)};
        ushort4 kp = {f2b(k.x), f2b(k.y), f2b(k.z), f2b(k.w)};
        ushort4 vp = {f2b(v.x), f2b(v.y), f2b(v.z), f2b(v.w)};
        *(ushort4*)&Qs[t * 72 + o * 4] = qp;
        *(ushort4*)&Ks[t * 72 + o * 4] = kp;
        *(ushort4*)&Vs[t * 72 + o * 4] = vp;
    }
    for (int idx = tid; idx < 2048; idx += 512) {   // Wv, Wo -> bf16 LDS
        int which = idx >> 10, rc = idx & 1023;
        int r = rc >> 4, c = rc & 15;
        float4 w = (which ? (const float4*)Wo : (const float4*)Wv)[r * 16 + c];
        ushort4 wp = {f2b(w.x), f2b(w.y), f2b(w.z), f2b(w.w)};
        unsigned short* dst = which ? Wo16 : Wv16;
        *(ushort4*)&dst[r * 72 + c * 4] = wp;
    }
    for (int idx = tid; idx < 768; idx += 512) {
        if (idx < 384) ((float4*)Wq_s)[idx]       = ((const float4*)cqw)[idx];
        else           ((float4*)Wk_s)[idx - 384] = ((const float4*)ckw)[idx - 384];
    }
    for (int idx = tid; idx < 72; idx += 512) {     // zero Q/K pad rows 36-39
        if (idx < 36) ((uint4*)&Qs[36 * 72])[idx] = z4;
        else          ((uint4*)&Ks[36 * 72])[idx - 36] = z4;
    }
    for (int idx = tid; idx < 160; idx += 512) ((uint4*)Mt)[idx] = z4;
    if (tid < 64) *(uint2*)&VhT[tid * 40 + 36] = make_uint2(0u, 0u);
    if (tid < 64) { cqb_s[tid] = cqb_g[tid]; g_s[tid] = gam[tid]; be_s[tid] = bet[tid]; }
    __syncthreads();   // barrier A

    // ================= Mt build + Vh projection (MFMA -> VhT transposed) =================
    for (int u = tid; u < 600; u += 512) {
        int j2 = u / 25, jp = u - j2 * 25;
        int wkc = (j2 & 7) * 3 + (j2 >> 3);
        float acc = 0.f;
        if (jp < 24) {
            int wqc = (jp & 7) * 3 + (jp >> 3);
            for (int c = 0; c < 64; ++c) acc += Wq_s[c * 24 + wqc] * Wk_s[c * 24 + wkc];
        } else {
            for (int c = 0; c < 64; ++c) acc += cqb_s[c] * Wk_s[c * 24 + wkc];
        }
        Mt[j2 * 40 + jp] = f2b(acc * 0.125f);
    }
    {
        #pragma unroll
        for (int tt = 0; tt < 2; ++tt) {
            int rt, ct;
            if (wave < 4) { rt = tt * 2; ct = wave; }
            else { if (tt) break; rt = 1; ct = wave - 4; }
            float bvv = bv[ct * 16 + c15];
            f32x4 d = {bvv, bvv, bvv, bvv};
            int rc = min(rt * 16 + c15, 35);
            uint4 A0 = *(const uint4*)&Vs[rc * 72 + g * 8];
            uint4 A1 = *(const uint4*)&Vs[rc * 72 + 32 + g * 8];
            uint4 B0 = *(const uint4*)&Wv16[(ct * 16 + c15) * 72 + g * 8];
            uint4 B1 = *(const uint4*)&Wv16[(ct * 16 + c15) * 72 + 32 + g * 8];
            d = __builtin_amdgcn_mfma_f32_16x16x32_bf16(s8(A0), s8(B0), d, 0, 0, 0);
            d = __builtin_amdgcn_mfma_f32_16x16x32_bf16(s8(A1), s8(B1), d, 0, 0, 0);
            int ts = rt * 16 + g * 4;
            if (ts < 36) {   // rows ts..ts+3 valid (36 % 4 == 0)
                ushort4 o4 = {f2b(d[0]), f2b(d[1]), f2b(d[2]), f2b(d[3])};
                *(ushort4*)&VhT[(ct * 16 + c15) * 40 + ts] = o4;
            }
        }
    }
    __syncthreads();   // barrier B: Mt, VhT ready; Ubuf free for Z/P

    // ================= per-wave (wave = head) chain, barrier-free =================
    const int h8 = wave * 8;
    unsigned short* Ph = P_s + wave * 1440;     // [36][40] Z scratch, then P

    // ---- Z = [Aq | 1] @ Mt^T ----
    {
        uint4 BfZ[2];
        #pragma unroll
        for (int ct = 0; ct < 2; ++ct)
            BfZ[ct] = *(const uint4*)&Mt[(ct * 16 + c15) * 40 + g * 8];
        #pragma unroll
        for (int rt = 0; rt < 3; ++rt) {
            uint4 av;
            if (g == 3) { av = z4; av.x = 0x00003F80u; }   // bias col 24 = 1.0
            else {
                int row = rt * 16 + c15 + g - 2;
                int rcq = min(max(row, 0), 39);
                av = *(const uint4*)&Qs[rcq * 72 + h8];
                if (row < 0) av = z4;
            }
            f32x4 zz[2];
            #pragma unroll
            for (int ct = 0; ct < 2; ++ct) {
                f32x4 zero = {0.f, 0.f, 0.f, 0.f};
                zz[ct] = __builtin_amdgcn_mfma_f32_16x16x32_bf16(s8(av), s8(BfZ[ct]), zero, 0, 0, 0);
            }
            #pragma unroll
            for (int ct = 0; ct < 2; ++ct)
                #pragma unroll
                for (int r = 0; r < 4; ++r) {
                    int q = rt * 16 + g * 4 + r;
                    if (q < 36) Ph[q * 40 + ct * 16 + c15] = f2b(zz[ct][r]);
                }
        }
    }

    // ---- S = Z @ Ak^T, exp, P (overwrites Z region; wave-private, no barrier) ----
    {
        uint4 BfS[3], AfS[3];
        #pragma unroll
        for (int ct = 0; ct < 3; ++ct) {
            uint4 v = z4;
            if (g < 3) {
                int row = ct * 16 + c15 + g - 2;
                int rck = min(max(row, 0), 39);
                v = *(const uint4*)&Ks[rck * 72 + h8];
                if (row < 0) v = z4;
            }
            BfS[ct] = v;
        }
        #pragma unroll
        for (int rt = 0; rt < 3; ++rt) {
            int rc = min(rt * 16 + c15, 35);
            AfS[rt] = *(const uint4*)&Ph[rc * 40 + g * 8];
        }
        #pragma unroll
        for (int rt = 0; rt < 3; ++rt) {
            #pragma unroll
            for (int ct = 0; ct < 3; ++ct) {
                f32x4 zero = {0.f, 0.f, 0.f, 0.f};
                f32x4 s = __builtin_amdgcn_mfma_f32_16x16x32_bf16(s8(AfS[rt]), s8(BfS[ct]), zero, 0, 0, 0);
                #pragma unroll
                for (int r = 0; r < 4; ++r) {
                    int q = rt * 16 + g * 4 + r;
                    int k = ct * 16 + c15;
                    if (q < 36 && k < 40) {
                        float e = (k <= q) ? __expf(s[r]) : 0.f;
                        Ph[q * 40 + k] = f2b(e);
                    }
                }
            }
        }
    }

    // ---- ctx = P @ [Vh | 1] -> Ctx16 bf16 (col 8 of tile = esum) ----
    {
        const unsigned ONE2 = 0x3F803F80u;
        uint4 B0, B1;
        {
            int cc = min(h8 + c15, 63);
            if (c15 == 8) { B0 = make_uint4(ONE2, ONE2, ONE2, ONE2); B1 = make_uint4(ONE2, ONE2, 0u, 0u); }
            else {
                B0 = *(const uint4*)&VhT[cc * 40 + g * 8];
                B1 = (g == 0) ? *(const uint4*)&VhT[cc * 40 + 32] : z4;
            }
        }
        #pragma unroll
        for (int rt = 0; rt < 3; ++rt) {
            int rc = min(rt * 16 + c15, 35);
            uint4 A0 = *(const uint4*)&Ph[rc * 40 + g * 8];
            uint4 A1 = (g == 0) ? *(const uint4*)&Ph[rc * 40 + 32] : z4;
            f32x4 d = {0.f, 0.f, 0.f, 0.f};
            d = __builtin_amdgcn_mfma_f32_16x16x32_bf16(s8(A0), s8(B0), d, 0, 0, 0);
            d = __builtin_amdgcn_mfma_f32_16x16x32_bf16(s8(A1), s8(B1), d, 0, 0, 0);
            #pragma unroll
            for (int r = 0; r < 4; ++r) {
                int q = rt * 16 + g * 4 + r;
                float es = __shfl(d[r], (lane & 48) | 8);
                if (q < 36 && c15 < 8)
                    Ctx16[q * 72 + h8 + c15] = f2b(d[r] * __frcp_rn(es));
            }
        }
    }
    __syncthreads();   // barrier C: Ctx16 complete

    // ================= out-proj (MFMA) + residual -> OutS =================
    {
        #pragma unroll
        for (int tt = 0; tt < 2; ++tt) {
            int rt, ct;
            if (wave < 4) { rt = tt * 2; ct = wave; }
            else { if (tt) break; rt = 1; ct = wave - 4; }
            float bov = bo[ct * 16 + c15];
            f32x4 d = {bov, bov, bov, bov};
            int rc = min(rt * 16 + c15, 35);
            uint4 A0 = *(const uint4*)&Ctx16[rc * 72 + g * 8];
            uint4 A1 = *(const uint4*)&Ctx16[rc * 72 + 32 + g * 8];
            uint4 B0 = *(const uint4*)&Wo16[(ct * 16 + c15) * 72 + g * 8];
            uint4 B1 = *(const uint4*)&Wo16[(ct * 16 + c15) * 72 + 32 + g * 8];
            d = __builtin_amdgcn_mfma_f32_16x16x32_bf16(s8(A0), s8(B0), d, 0, 0, 0);
            d = __builtin_amdgcn_mfma_f32_16x16x32_bf16(s8(A1), s8(B1), d, 0, 0, 0);
            int o = ct * 16 + c15;
            #pragma unroll
            for (int r = 0; r < 4; ++r) {
                int t = rt * 16 + g * 4 + r;
                if (t < 36) {
                    size_t gi = ((size_t)(b * TT + t) * NN + n) * 64 + o;
                    OutS[t * 68 + o] = d[r] + X[gi];
                }
            }
        }
    }
    __syncthreads();   // barrier D: OutS ready (aliases dead Vs)

    // ================= LayerNorm =================
    for (int t = wave; t < TT; t += 8) {
        float acc = OutS[t * 68 + lane];
        float s1 = acc, s2 = acc * acc;
        #pragma unroll
        for (int off = 32; off; off >>= 1) {
            s1 += __shfl_xor(s1, off);
            s2 += __shfl_xor(s2, off);
        }
        float mu  = s1 * (1.f / 64.f);
        float var = s2 * (1.f / 64.f) - mu * mu;
        size_t gi = ((size_t)(b * TT + t) * NN + n) * 64 + lane;
        out[gi] = (acc - mu) * rsqrtf(var + LN_EPS) * g_s[lane] + be_s[lane];
    }
}

extern "C" void kernel_launch(void* const* d_in, const int* in_sizes, int n_in,
                              void* d_out, int out_size, void* d_ws, size_t ws_size,
                              hipStream_t stream) {
    const float* X   = (const float*)d_in[0];
    const float* Q   = (const float*)d_in[1];
    const float* K   = (const float*)d_in[2];
    const float* V   = (const float*)d_in[3];
    const float* Wv  = (const float*)d_in[4];
    const float* bv  = (const float*)d_in[5];
    const float* Wo  = (const float*)d_in[6];
    const float* bo  = (const float*)d_in[7];
    const float* cqw = (const float*)d_in[8];
    const float* cqb = (const float*)d_in[9];
    const float* ckw = (const float*)d_in[10];
    // d_in[11] (conv_k_b) cancels in softmax -> unused
    const float* gam = (const float*)d_in[12];
    const float* bet = (const float*)d_in[13];
    float* out = (float*)d_out;

    dim3 grid(16 * NN), block(512);
    hipLaunchKernelGGL(fused_attn7, grid, block, 0, stream,
                       X, Q, K, V, Wv, bv, Wo, bo, cqw, cqb, ckw, gam, bet, out);
}

// Round 8
// 93.098 us; speedup vs baseline: 8.8395x; 1.2379x over previous
//
#include <hip/hip_runtime.h>

#define TT 36
#define NN 207
#define LN_EPS 1e-5f

typedef __attribute__((ext_vector_type(8))) short short8;
typedef __attribute__((ext_vector_type(4))) float f32x4;

__device__ __forceinline__ unsigned short f2b(float f) {
    unsigned u = __float_as_uint(f);
    return (unsigned short)((u + 0x7FFFu + ((u >> 16) & 1u)) >> 16);
}
__device__ __forceinline__ short8 s8(uint4 u) { union { uint4 a; short8 b; } x; x.a = u; return x.b; }

// ws layout (ushort units): [0..1023] Mt [32][32]; [1024..5119] Wv16 [64][64]; [5120..9215] Wo16 [64][64]
__global__ __launch_bounds__(512) void prep_kernel(
    const float* __restrict__ Wv, const float* __restrict__ Wo,
    const float* __restrict__ cqw, const float* __restrict__ cqb,
    const float* __restrict__ ckw, unsigned short* __restrict__ ws)
{
    const int tid = threadIdx.x;
    for (int i = tid; i < 4096; i += 512) {
        ws[1024 + i] = f2b(Wv[i]);
        ws[5120 + i] = f2b(Wo[i]);
    }
    for (int u = tid; u < 1024; u += 512) {
        int j2 = u >> 5, jp = u & 31;
        float acc = 0.f;
        if (j2 < 24 && jp < 25) {
            int wkc = (j2 & 7) * 3 + (j2 >> 3);
            if (jp < 24) {
                int wqc = (jp & 7) * 3 + (jp >> 3);
                for (int c = 0; c < 64; ++c) acc += cqw[c * 24 + wqc] * ckw[c * 24 + wkc];
            } else {
                for (int c = 0; c < 64; ++c) acc += cqb[c] * ckw[c * 24 + wkc];
            }
            acc *= 0.125f;
        }
        ws[u] = f2b(acc);
    }
}

__global__ __launch_bounds__(512, 4) void fused_attn8(
    const float* __restrict__ X, const float* __restrict__ Qg,
    const float* __restrict__ Kg, const float* __restrict__ Vg,
    const float* __restrict__ bv, const float* __restrict__ bo,
    const float* __restrict__ gam, const float* __restrict__ bet,
    const unsigned short* __restrict__ ws,
    float* __restrict__ out)
{
    __shared__ __align__(16) unsigned short Qs[40 * 72];   // Q bf16 (rows 36-39 zero); later Ctx16 [36][72]
    __shared__ __align__(16) unsigned short Ks[40 * 72];
    __shared__ __align__(16) unsigned short VhT[64 * 40];  // projected V transposed [o][t], t=36..39 zero
    __shared__ __align__(16) unsigned char  VsOut[9792];   // Vs bf16 [36][72] -> OutS f32 [36][68]
    __shared__ __align__(16) unsigned short P_all[8 * 36 * 40]; // per-wave Z/P [36][40]

    unsigned short* Vs    = (unsigned short*)VsOut;
    float*          OutS  = (float*)VsOut;
    unsigned short* Ctx16 = Qs;

    const unsigned short* MtG = ws;          // [32][32]
    const unsigned short* WvG = ws + 1024;   // [64][64]
    const unsigned short* WoG = ws + 5120;   // [64][64]

    const int tid  = threadIdx.x;
    const int lane = tid & 63;
    const int wave = tid >> 6;
    const int g    = lane >> 4, c15 = lane & 15;
    const int b    = blockIdx.x / NN;
    const int n    = blockIdx.x % NN;
    const uint4 z4 = {0u, 0u, 0u, 0u};

    // ================= staging =================
    const float4* Q4 = (const float4*)(Qg + (size_t)(b * TT * NN + n) * 64);
    const float4* K4 = (const float4*)(Kg + (size_t)(b * TT * NN + n) * 64);
    const float4* V4 = (const float4*)(Vg + (size_t)(b * TT * NN + n) * 64);
    for (int idx = tid; idx < TT * 16; idx += 512) {
        int t = idx >> 4, o = idx & 15;
        float4 q = Q4[t * 3312 + o];
        float4 k = K4[t * 3312 + o];
        float4 v = V4[t * 3312 + o];
        ushort4 qp = {f2b(q.x), f2b(q.y), f2b(q.z), f2b(q.w)};
        ushort4 kp = {f2b(k.x), f2b(k.y), f2b(k.z), f2b(k.w)};
        ushort4 vp = {f2b(v.x), f2b(v.y), f2b(v.z), f2b(v.w)};
        *(ushort4*)&Qs[t * 72 + o * 4] = qp;
        *(ushort4*)&Ks[t * 72 + o * 4] = kp;
        *(ushort4*)&Vs[t * 72 + o * 4] = vp;
    }
    for (int idx = tid; idx < 72; idx += 512) {     // zero Q/K pad rows 36-39
        if (idx < 36) ((uint4*)&Qs[36 * 72])[idx] = z4;
        else          ((uint4*)&Ks[36 * 72])[idx - 36] = z4;
    }
    if (tid < 64) *(uint2*)&VhT[tid * 40 + 36] = make_uint2(0u, 0u);
    __syncthreads();   // barrier A

    // ================= Vh proj (MFMA -> VhT transposed) =================
    {
        #pragma unroll
        for (int tt = 0; tt < 2; ++tt) {
            int rt, ct;
            if (wave < 4) { rt = tt * 2; ct = wave; }
            else { if (tt) break; rt = 1; ct = wave - 4; }
            float bvv = bv[ct * 16 + c15];
            f32x4 d = {bvv, bvv, bvv, bvv};
            int rc = min(rt * 16 + c15, 35);
            uint4 A0 = *(const uint4*)&Vs[rc * 72 + g * 8];
            uint4 A1 = *(const uint4*)&Vs[rc * 72 + 32 + g * 8];
            uint4 B0 = *(const uint4*)&WvG[(ct * 16 + c15) * 64 + g * 8];
            uint4 B1 = *(const uint4*)&WvG[(ct * 16 + c15) * 64 + 32 + g * 8];
            d = __builtin_amdgcn_mfma_f32_16x16x32_bf16(s8(A0), s8(B0), d, 0, 0, 0);
            d = __builtin_amdgcn_mfma_f32_16x16x32_bf16(s8(A1), s8(B1), d, 0, 0, 0);
            int ts = rt * 16 + g * 4;
            if (ts < 36) {
                ushort4 o4 = {f2b(d[0]), f2b(d[1]), f2b(d[2]), f2b(d[3])};
                *(ushort4*)&VhT[(ct * 16 + c15) * 40 + ts] = o4;
            }
        }
    }

    // ================= Z = [Aq | 1] @ Mt^T (per wave = head) =================
    const int h8 = wave * 8;
    unsigned short* Ph = P_all + wave * 1440;   // [36][40]
    {
        uint4 BfZ[2];
        #pragma unroll
        for (int ct = 0; ct < 2; ++ct)
            BfZ[ct] = *(const uint4*)&MtG[(ct * 16 + c15) * 32 + g * 8];
        #pragma unroll
        for (int rt = 0; rt < 3; ++rt) {
            uint4 av;
            if (g == 3) { av = z4; av.x = 0x00003F80u; }   // bias col 24 = 1.0
            else {
                int row = rt * 16 + c15 + g - 2;
                int rcq = min(max(row, 0), 39);
                av = *(const uint4*)&Qs[rcq * 72 + h8];
                if (row < 0) av = z4;
            }
            f32x4 zz[2];
            #pragma unroll
            for (int ct = 0; ct < 2; ++ct) {
                f32x4 zero = {0.f, 0.f, 0.f, 0.f};
                zz[ct] = __builtin_amdgcn_mfma_f32_16x16x32_bf16(s8(av), s8(BfZ[ct]), zero, 0, 0, 0);
            }
            #pragma unroll
            for (int ct = 0; ct < 2; ++ct)
                #pragma unroll
                for (int r = 0; r < 4; ++r) {
                    int q = rt * 16 + g * 4 + r;
                    if (q < 36) Ph[q * 40 + ct * 16 + c15] = f2b(zz[ct][r]);
                }
        }
    }
    __syncthreads();   // barrier B: all Z done (Qs free), VhT complete

    // ================= S = Z @ Ak^T, exp -> P (wave-private) =================
    {
        uint4 BfS[3], AfS[3];
        #pragma unroll
        for (int ct = 0; ct < 3; ++ct) {
            uint4 v = z4;
            if (g < 3) {
                int row = ct * 16 + c15 + g - 2;
                int rck = min(max(row, 0), 39);
                v = *(const uint4*)&Ks[rck * 72 + h8];
                if (row < 0) v = z4;
            }
            BfS[ct] = v;
        }
        #pragma unroll
        for (int rt = 0; rt < 3; ++rt) {
            int rc = min(rt * 16 + c15, 35);
            AfS[rt] = *(const uint4*)&Ph[rc * 40 + g * 8];
        }
        #pragma unroll
        for (int rt = 0; rt < 3; ++rt) {
            #pragma unroll
            for (int ct = 0; ct < 3; ++ct) {
                f32x4 zero = {0.f, 0.f, 0.f, 0.f};
                f32x4 s = __builtin_amdgcn_mfma_f32_16x16x32_bf16(s8(AfS[rt]), s8(BfS[ct]), zero, 0, 0, 0);
                #pragma unroll
                for (int r = 0; r < 4; ++r) {
                    int q = rt * 16 + g * 4 + r;
                    int k = ct * 16 + c15;
                    if (q < 36 && k < 40) {
                        float e = (k <= q) ? __expf(s[r]) : 0.f;
                        Ph[q * 40 + k] = f2b(e);
                    }
                }
            }
        }
    }

    // ================= ctx = P @ [Vh | 1] -> Ctx16 (aliases Qs) =================
    {
        const unsigned ONE2 = 0x3F803F80u;
        uint4 B0, B1;
        {
            int cc = min(h8 + c15, 63);
            if (c15 == 8) { B0 = make_uint4(ONE2, ONE2, ONE2, ONE2); B1 = make_uint4(ONE2, ONE2, 0u, 0u); }
            else {
                B0 = *(const uint4*)&VhT[cc * 40 + g * 8];
                B1 = (g == 0) ? *(const uint4*)&VhT[cc * 40 + 32] : z4;
            }
        }
        #pragma unroll
        for (int rt = 0; rt < 3; ++rt) {
            int rc = min(rt * 16 + c15, 35);
            uint4 A0 = *(const uint4*)&Ph[rc * 40 + g * 8];
            uint4 A1 = (g == 0) ? *(const uint4*)&Ph[rc * 40 + 32] : z4;
            f32x4 d = {0.f, 0.f, 0.f, 0.f};
            d = __builtin_amdgcn_mfma_f32_16x16x32_bf16(s8(A0), s8(B0), d, 0, 0, 0);
            d = __builtin_amdgcn_mfma_f32_16x16x32_bf16(s8(A1), s8(B1), d, 0, 0, 0);
            #pragma unroll
            for (int r = 0; r < 4; ++r) {
                int q = rt * 16 + g * 4 + r;
                float es = __shfl(d[r], (lane & 48) | 8);
                if (q < 36 && c15 < 8)
                    Ctx16[q * 72 + h8 + c15] = f2b(d[r] * __frcp_rn(es));
            }
        }
    }
    __syncthreads();   // barrier C: Ctx16 complete

    // ================= out-proj (MFMA) + residual -> OutS (aliases Vs) =================
    {
        #pragma unroll
        for (int tt = 0; tt < 2; ++tt) {
            int rt, ct;
            if (wave < 4) { rt = tt * 2; ct = wave; }
            else { if (tt) break; rt = 1; ct = wave - 4; }
            float bov = bo[ct * 16 + c15];
            f32x4 d = {bov, bov, bov, bov};
            int rc = min(rt * 16 + c15, 35);
            uint4 A0 = *(const uint4*)&Ctx16[rc * 72 + g * 8];
            uint4 A1 = *(const uint4*)&Ctx16[rc * 72 + 32 + g * 8];
            uint4 B0 = *(const uint4*)&WoG[(ct * 16 + c15) * 64 + g * 8];
            uint4 B1 = *(const uint4*)&WoG[(ct * 16 + c15) * 64 + 32 + g * 8];
            d = __builtin_amdgcn_mfma_f32_16x16x32_bf16(s8(A0), s8(B0), d, 0, 0, 0);
            d = __builtin_amdgcn_mfma_f32_16x16x32_bf16(s8(A1), s8(B1), d, 0, 0, 0);
            int o = ct * 16 + c15;
            #pragma unroll
            for (int r = 0; r < 4; ++r) {
                int t = rt * 16 + g * 4 + r;
                if (t < 36) {
                    size_t gi = ((size_t)(b * TT + t) * NN + n) * 64 + o;
                    OutS[t * 68 + o] = d[r] + X[gi];
                }
            }
        }
    }
    __syncthreads();   // barrier D

    // ================= LayerNorm =================
    {
        float gamr = gam[lane], betr = bet[lane];
        for (int t = wave; t < TT; t += 8) {
            float acc = OutS[t * 68 + lane];
            float s1 = acc, s2 = acc * acc;
            #pragma unroll
            for (int off = 32; off; off >>= 1) {
                s1 += __shfl_xor(s1, off);
                s2 += __shfl_xor(s2, off);
            }
            float mu  = s1 * (1.f / 64.f);
            float var = s2 * (1.f / 64.f) - mu * mu;
            size_t gi = ((size_t)(b * TT + t) * NN + n) * 64 + lane;
            out[gi] = (acc - mu) * rsqrtf(var + LN_EPS) * gamr + betr;
        }
    }
}

extern "C" void kernel_launch(void* const* d_in, const int* in_sizes, int n_in,
                              void* d_out, int out_size, void* d_ws, size_t ws_size,
                              hipStream_t stream) {
    const float* X   = (const float*)d_in[0];
    const float* Q   = (const float*)d_in[1];
    const float* K   = (const float*)d_in[2];
    const float* V   = (const float*)d_in[3];
    const float* Wv  = (const float*)d_in[4];
    const float* bv  = (const float*)d_in[5];
    const float* Wo  = (const float*)d_in[6];
    const float* bo  = (const float*)d_in[7];
    const float* cqw = (const float*)d_in[8];
    const float* cqb = (const float*)d_in[9];
    const float* ckw = (const float*)d_in[10];
    // d_in[11] (conv_k_b) cancels in softmax -> unused
    const float* gam = (const float*)d_in[12];
    const float* bet = (const float*)d_in[13];
    float* out = (float*)d_out;
    unsigned short* ws = (unsigned short*)d_ws;

    hipLaunchKernelGGL(prep_kernel, dim3(1), dim3(512), 0, stream, Wv, Wo, cqw, cqb, ckw, ws);
    hipLaunchKernelGGL(fused_attn8, dim3(16 * NN), dim3(512), 0, stream,
                       X, Q, K, V, bv, bo, gam, bet, ws, out);
}

// Round 9
// 88.189 us; speedup vs baseline: 9.3316x; 1.0557x over previous
//
#include <hip/hip_runtime.h>

#define TT 36
#define NN 207
#define LN_EPS 1e-5f

typedef __attribute__((ext_vector_type(8))) short short8;
typedef __attribute__((ext_vector_type(4))) float f32x4;

__device__ __forceinline__ unsigned short f2b(float f) {
    unsigned u = __float_as_uint(f);
    return (unsigned short)((u + 0x7FFFu + ((u >> 16) & 1u)) >> 16);
}
__device__ __forceinline__ short8 s8(uint4 u) { union { uint4 a; short8 b; } x; x.a = u; return x.b; }

// ws layout (ushort units): [0..1023] Mt [32][32]; [1024..5119] Wv16 [64][64]; [5120..9215] Wo16 [64][64]
__global__ __launch_bounds__(512) void prep_kernel(
    const float* __restrict__ Wv, const float* __restrict__ Wo,
    const float* __restrict__ cqw, const float* __restrict__ cqb,
    const float* __restrict__ ckw, unsigned short* __restrict__ ws)
{
    const int tid = threadIdx.x;
    for (int i = tid; i < 4096; i += 512) {
        ws[1024 + i] = f2b(Wv[i]);
        ws[5120 + i] = f2b(Wo[i]);
    }
    for (int u = tid; u < 1024; u += 512) {
        int j2 = u >> 5, jp = u & 31;
        float acc = 0.f;
        if (j2 < 24 && jp < 25) {
            int wkc = (j2 & 7) * 3 + (j2 >> 3);
            if (jp < 24) {
                int wqc = (jp & 7) * 3 + (jp >> 3);
                for (int c = 0; c < 64; ++c) acc += cqw[c * 24 + wqc] * ckw[c * 24 + wkc];
            } else {
                for (int c = 0; c < 64; ++c) acc += cqb[c] * ckw[c * 24 + wkc];
            }
            acc *= 0.125f;
        }
        ws[u] = f2b(acc);
    }
}

__global__ __launch_bounds__(512, 4) void fused_attn9(
    const float* __restrict__ X, const float* __restrict__ Qg,
    const float* __restrict__ Kg, const float* __restrict__ Vg,
    const float* __restrict__ bv, const float* __restrict__ bo,
    const float* __restrict__ gam, const float* __restrict__ bet,
    const unsigned short* __restrict__ ws,
    float* __restrict__ out)
{
    // 39,680 B total -> 4 blocks/CU
    __shared__ __align__(16) unsigned short Qs[40 * 72];   // Q bf16 (rows 36-39 zero); later Ctx16 [36][72]
    __shared__ __align__(16) unsigned short Ks[40 * 72];
    __shared__ __align__(16) unsigned short VhT[64 * 40];  // projected V transposed [o][t], t=36..39 zero
    __shared__ __align__(16) unsigned char  Pbuf[23040];   // phase 1: Vs bf16 [36][72]; phase 2: per-wave Z/P [8][36][40]; phase 3: OutS f32 [36][68]

    unsigned short* Vs    = (unsigned short*)Pbuf;
    float*          OutS  = (float*)Pbuf;
    unsigned short* Ctx16 = Qs;

    const unsigned short* MtG = ws;          // [32][32]
    const unsigned short* WvG = ws + 1024;   // [64][64]
    const unsigned short* WoG = ws + 5120;   // [64][64]

    const int tid  = threadIdx.x;
    const int lane = tid & 63;
    const int wave = tid >> 6;
    const int g    = lane >> 4, c15 = lane & 15;
    const int b    = blockIdx.x / NN;
    const int n    = blockIdx.x % NN;
    const uint4 z4 = {0u, 0u, 0u, 0u};

    // ================= staging =================
    const float4* Q4 = (const float4*)(Qg + (size_t)(b * TT * NN + n) * 64);
    const float4* K4 = (const float4*)(Kg + (size_t)(b * TT * NN + n) * 64);
    const float4* V4 = (const float4*)(Vg + (size_t)(b * TT * NN + n) * 64);
    for (int idx = tid; idx < TT * 16; idx += 512) {
        int t = idx >> 4, o = idx & 15;
        float4 q = Q4[t * 3312 + o];
        float4 k = K4[t * 3312 + o];
        float4 v = V4[t * 3312 + o];
        ushort4 qp = {f2b(q.x), f2b(q.y), f2b(q.z), f2b(q.w)};
        ushort4 kp = {f2b(k.x), f2b(k.y), f2b(k.z), f2b(k.w)};
        ushort4 vp = {f2b(v.x), f2b(v.y), f2b(v.z), f2b(v.w)};
        *(ushort4*)&Qs[t * 72 + o * 4] = qp;
        *(ushort4*)&Ks[t * 72 + o * 4] = kp;
        *(ushort4*)&Vs[t * 72 + o * 4] = vp;
    }
    for (int idx = tid; idx < 72; idx += 512) {     // zero Q/K pad rows 36-39
        if (idx < 36) ((uint4*)&Qs[36 * 72])[idx] = z4;
        else          ((uint4*)&Ks[36 * 72])[idx - 36] = z4;
    }
    if (tid < 64) *(uint2*)&VhT[tid * 40 + 36] = make_uint2(0u, 0u);
    __syncthreads();   // barrier A: staging complete

    // ================= Vh proj (MFMA -> VhT transposed), reads Vs =================
    {
        #pragma unroll
        for (int tt = 0; tt < 2; ++tt) {
            int rt, ct;
            if (wave < 4) { rt = tt * 2; ct = wave; }
            else { if (tt) break; rt = 1; ct = wave - 4; }
            float bvv = bv[ct * 16 + c15];
            f32x4 d = {bvv, bvv, bvv, bvv};
            int rc = min(rt * 16 + c15, 35);
            uint4 A0 = *(const uint4*)&Vs[rc * 72 + g * 8];
            uint4 A1 = *(const uint4*)&Vs[rc * 72 + 32 + g * 8];
            uint4 B0 = *(const uint4*)&WvG[(ct * 16 + c15) * 64 + g * 8];
            uint4 B1 = *(const uint4*)&WvG[(ct * 16 + c15) * 64 + 32 + g * 8];
            d = __builtin_amdgcn_mfma_f32_16x16x32_bf16(s8(A0), s8(B0), d, 0, 0, 0);
            d = __builtin_amdgcn_mfma_f32_16x16x32_bf16(s8(A1), s8(B1), d, 0, 0, 0);
            int ts = rt * 16 + g * 4;
            if (ts < 36) {
                ushort4 o4 = {f2b(d[0]), f2b(d[1]), f2b(d[2]), f2b(d[3])};
                *(ushort4*)&VhT[(ct * 16 + c15) * 40 + ts] = o4;
            }
        }
    }
    __syncthreads();   // barrier A2: Vs dead; Pbuf now owned by per-wave Z/P

    // ================= Z = [Aq | 1] @ Mt^T (per wave = head) =================
    const int h8 = wave * 8;
    unsigned short* Ph = (unsigned short*)Pbuf + wave * 1440;   // [36][40]
    {
        uint4 BfZ[2];
        #pragma unroll
        for (int ct = 0; ct < 2; ++ct)
            BfZ[ct] = *(const uint4*)&MtG[(ct * 16 + c15) * 32 + g * 8];
        #pragma unroll
        for (int rt = 0; rt < 3; ++rt) {
            uint4 av;
            if (g == 3) { av = z4; av.x = 0x00003F80u; }   // bias col 24 = 1.0
            else {
                int row = rt * 16 + c15 + g - 2;
                int rcq = min(max(row, 0), 39);
                av = *(const uint4*)&Qs[rcq * 72 + h8];
                if (row < 0) av = z4;
            }
            f32x4 zz[2];
            #pragma unroll
            for (int ct = 0; ct < 2; ++ct) {
                f32x4 zero = {0.f, 0.f, 0.f, 0.f};
                zz[ct] = __builtin_amdgcn_mfma_f32_16x16x32_bf16(s8(av), s8(BfZ[ct]), zero, 0, 0, 0);
            }
            #pragma unroll
            for (int ct = 0; ct < 2; ++ct)
                #pragma unroll
                for (int r = 0; r < 4; ++r) {
                    int q = rt * 16 + g * 4 + r;
                    if (q < 36) Ph[q * 40 + ct * 16 + c15] = f2b(zz[ct][r]);
                }
        }
    }
    __syncthreads();   // barrier B: Qs dead (Ctx16 may write); Z complete

    // ================= S = Z @ Ak^T, exp -> P (wave-private) =================
    {
        uint4 BfS[3], AfS[3];
        #pragma unroll
        for (int ct = 0; ct < 3; ++ct) {
            uint4 v = z4;
            if (g < 3) {
                int row = ct * 16 + c15 + g - 2;
                int rck = min(max(row, 0), 39);
                v = *(const uint4*)&Ks[rck * 72 + h8];
                if (row < 0) v = z4;
            }
            BfS[ct] = v;
        }
        #pragma unroll
        for (int rt = 0; rt < 3; ++rt) {
            int rc = min(rt * 16 + c15, 35);
            AfS[rt] = *(const uint4*)&Ph[rc * 40 + g * 8];
        }
        #pragma unroll
        for (int rt = 0; rt < 3; ++rt) {
            #pragma unroll
            for (int ct = 0; ct < 3; ++ct) {
                f32x4 zero = {0.f, 0.f, 0.f, 0.f};
                f32x4 s = __builtin_amdgcn_mfma_f32_16x16x32_bf16(s8(AfS[rt]), s8(BfS[ct]), zero, 0, 0, 0);
                #pragma unroll
                for (int r = 0; r < 4; ++r) {
                    int q = rt * 16 + g * 4 + r;
                    int k = ct * 16 + c15;
                    if (q < 36 && k < 40) {
                        float e = (k <= q) ? __expf(s[r]) : 0.f;
                        Ph[q * 40 + k] = f2b(e);
                    }
                }
            }
        }
    }

    // ================= ctx = P @ [Vh | 1] -> Ctx16 (aliases Qs) =================
    {
        const unsigned ONE2 = 0x3F803F80u;
        uint4 B0, B1;
        {
            int cc = min(h8 + c15, 63);
            if (c15 == 8) { B0 = make_uint4(ONE2, ONE2, ONE2, ONE2); B1 = make_uint4(ONE2, ONE2, 0u, 0u); }
            else {
                B0 = *(const uint4*)&VhT[cc * 40 + g * 8];
                B1 = (g == 0) ? *(const uint4*)&VhT[cc * 40 + 32] : z4;
            }
        }
        #pragma unroll
        for (int rt = 0; rt < 3; ++rt) {
            int rc = min(rt * 16 + c15, 35);
            uint4 A0 = *(const uint4*)&Ph[rc * 40 + g * 8];
            uint4 A1 = (g == 0) ? *(const uint4*)&Ph[rc * 40 + 32] : z4;
            f32x4 d = {0.f, 0.f, 0.f, 0.f};
            d = __builtin_amdgcn_mfma_f32_16x16x32_bf16(s8(A0), s8(B0), d, 0, 0, 0);
            d = __builtin_amdgcn_mfma_f32_16x16x32_bf16(s8(A1), s8(B1), d, 0, 0, 0);
            #pragma unroll
            for (int r = 0; r < 4; ++r) {
                int q = rt * 16 + g * 4 + r;
                float es = __shfl(d[r], (lane & 48) | 8);
                if (q < 36 && c15 < 8)
                    Ctx16[q * 72 + h8 + c15] = f2b(d[r] * __frcp_rn(es));
            }
        }
    }
    __syncthreads();   // barrier C: Ctx16 complete; Pbuf dead -> OutS owns it

    // ================= out-proj (MFMA) + residual -> OutS (aliases Pbuf) =================
    {
        #pragma unroll
        for (int tt = 0; tt < 2; ++tt) {
            int rt, ct;
            if (wave < 4) { rt = tt * 2; ct = wave; }
            else { if (tt) break; rt = 1; ct = wave - 4; }
            float bov = bo[ct * 16 + c15];
            f32x4 d = {bov, bov, bov, bov};
            int rc = min(rt * 16 + c15, 35);
            uint4 A0 = *(const uint4*)&Ctx16[rc * 72 + g * 8];
            uint4 A1 = *(const uint4*)&Ctx16[rc * 72 + 32 + g * 8];
            uint4 B0 = *(const uint4*)&WoG[(ct * 16 + c15) * 64 + g * 8];
            uint4 B1 = *(const uint4*)&WoG[(ct * 16 + c15) * 64 + 32 + g * 8];
            d = __builtin_amdgcn_mfma_f32_16x16x32_bf16(s8(A0), s8(B0), d, 0, 0, 0);
            d = __builtin_amdgcn_mfma_f32_16x16x32_bf16(s8(A1), s8(B1), d, 0, 0, 0);
            int o = ct * 16 + c15;
            #pragma unroll
            for (int r = 0; r < 4; ++r) {
                int t = rt * 16 + g * 4 + r;
                if (t < 36) {
                    size_t gi = ((size_t)(b * TT + t) * NN + n) * 64 + o;
                    OutS[t * 68 + o] = d[r] + X[gi];
                }
            }
        }
    }
    __syncthreads();   // barrier D

    // ================= LayerNorm =================
    {
        float gamr = gam[lane], betr = bet[lane];
        for (int t = wave; t < TT; t += 8) {
            float acc = OutS[t * 68 + lane];
            float s1 = acc, s2 = acc * acc;
            #pragma unroll
            for (int off = 32; off; off >>= 1) {
                s1 += __shfl_xor(s1, off);
                s2 += __shfl_xor(s2, off);
            }
            float mu  = s1 * (1.f / 64.f);
            float var = s2 * (1.f / 64.f) - mu * mu;
            size_t gi = ((size_t)(b * TT + t) * NN + n) * 64 + lane;
            out[gi] = (acc - mu) * rsqrtf(var + LN_EPS) * gamr + betr;
        }
    }
}

extern "C" void kernel_launch(void* const* d_in, const int* in_sizes, int n_in,
                              void* d_out, int out_size, void* d_ws, size_t ws_size,
                              hipStream_t stream) {
    const float* X   = (const float*)d_in[0];
    const float* Q   = (const float*)d_in[1];
    const float* K   = (const float*)d_in[2];
    const float* V   = (const float*)d_in[3];
    const float* Wv  = (const float*)d_in[4];
    const float* bv  = (const float*)d_in[5];
    const float* Wo  = (const float*)d_in[6];
    const float* bo  = (const float*)d_in[7];
    const float* cqw = (const float*)d_in[8];
    const float* cqb = (const float*)d_in[9];
    const float* ckw = (const float*)d_in[10];
    // d_in[11] (conv_k_b) cancels in softmax -> unused
    const float* gam = (const float*)d_in[12];
    const float* bet = (const float*)d_in[13];
    float* out = (float*)d_out;
    unsigned short* ws = (unsigned short*)d_ws;

    hipLaunchKernelGGL(prep_kernel, dim3(1), dim3(512), 0, stream, Wv, Wo, cqw, cqb, ckw, ws);
    hipLaunchKernelGGL(fused_attn9, dim3(16 * NN), dim3(512), 0, stream,
                       X, Q, K, V, bv, bo, gam, bet, ws, out);
}